// Round 6
// baseline (2396.430 us; speedup 1.0000x reference)
//
#include <hip/hip_runtime.h>
#include <cstddef>

#define DEV __device__ __forceinline__
DEV float lrelu(float x){ return x >= 0.0f ? x : 0.2f*x; }
typedef _Float16 f16;
typedef _Float16 f16x8 __attribute__((ext_vector_type(8)));
typedef float f32x4 __attribute__((ext_vector_type(4)));

// Problem dims: B=512, IN=512, CB=8, HD=256, CH=2048, CC=2560, EXP=128, FC1=1024, OUT=512
constexpr int NXPT = 512*512;     // dense support points (b,l<512)

// ---------------- workspace layout (float offsets) ----------------
constexpr size_t O_H1  = 0;                       // 512x1024 f32
constexpr size_t O_H2  = O_H1 + 512*1024;         // 512x1024 f32
constexpr size_t O_L   = O_H2 + 512*1024;         // 512x2048 f32 (c3 logits; dead after k_sel)
constexpr size_t O_SEL = O_L  + 512*2048;         // int32 512x256
constexpr size_t O_S   = O_SEL + 512*256;
constexpr size_t O_S2  = O_S + 512;
constexpr size_t O_VAL = O_S2 + 512;
constexpr size_t O_PRM = O_VAL + 512;
// params sub-offsets (within PRM)
constexpr size_t P_SC1=0, P_SH1=1024, P_SC2=2048, P_SH2=3072, P_SC3=4096, P_SH3=6144;
constexpr size_t P_A1=8192, P_C1=8224, P_EW2T=8256 /*2048*/;
constexpr size_t P_ACC2=18496 /*128*/, P_ACC3=18624 /*256*/;
constexpr size_t P_SCE2=18880, P_SHE2=18944, P_SCE3=19008, P_SHE3=19136;
constexpr size_t P_U0=19264 /*128*/, P_FTOT=19392 /*1024*/;
constexpr size_t P_SCF1=20416, P_SHF1=21440;
constexpr size_t P_SCD1=22464, P_SHD1=22528, P_SCD2=22592, P_SHD2=22624;
constexpr size_t PRM_SIZE = 32768;
// weight copies + stats accumulators + V2s ALIAS the dead L buffer (written after k_sel)
constexpr size_t O_FW1H = O_L;                    // f16 1024x512   (262144 floats)
constexpr size_t O_FW2H = O_L + 262144;           // f16 512x1024   (262144 floats)
constexpr size_t O_ACCF = O_L + 524288;           // f32 2048
constexpr size_t O_ACCD1= O_ACCF + 2048;          // f32 128
constexpr size_t O_ACCD2= O_ACCD1 + 128;          // f32 64
constexpr size_t O_DW1H = O_L + 528384;           // f16 64x128  (4096 floats)
constexpr size_t O_EW3H = O_L + 532480;           // f16 128x64  (4096 floats)
constexpr size_t O_V2SS = O_L + 536576;           // f32 513x64  (32832 floats)
constexpr size_t O_U1  = O_PRM + PRM_SIZE;        // 512x128 f32
constexpr size_t O_P1  = O_U1 + 512*128;          // 512x1024 f32
constexpr size_t O_FZT = O_P1 + 512*1024;         // 2048x1024 f32 (fW1 z-part transposed)
constexpr size_t O_V3S = O_FZT + (size_t)2048*1024;   // 513x128 f32
constexpr size_t O_BIG1= O_V3S + 513*128;             // f16 512*128*512  (V3xT, later out7)
constexpr size_t O_BIG2= O_BIG1 + (size_t)512*512*128/2; // f16 512*128*1024 (out6T), later d1p+d2p f32
constexpr size_t O_D1  = O_BIG2;                      // f32 512*64*512 (aliases out6T)
constexpr size_t O_D2  = O_BIG2 + (size_t)512*64*512; // f32 512*32*512
constexpr size_t O_V2X = O_BIG2;                      // f16 512*512*64 (33MB) aliases out6T region pre-fw1? NO — see note
// NOTE: V2x must live until k_mfma_e3; out6T written by fw1 AFTER e-path done. BIG2 region is
// 512*1024*128 f16 = 128MB; V2x needs 33MB. Place V2x at the TAIL of BIG2 so out6T (written
// later, full region) only overwrites it after V2x is dead.  Actually out6T IS the full region.
// V2x dead after k_mfma_e3; fw1 (writes out6T) runs after -> safe to alias anywhere in BIG2.
constexpr size_t O_END = O_BIG2 + (size_t)512*1024*128/2;   // ~211 MB (unchanged)

#define FMA44(av,bv) do{ \
  acc[0][0]=fmaf(av.x,bv.x,acc[0][0]); acc[0][1]=fmaf(av.x,bv.y,acc[0][1]); \
  acc[0][2]=fmaf(av.x,bv.z,acc[0][2]); acc[0][3]=fmaf(av.x,bv.w,acc[0][3]); \
  acc[1][0]=fmaf(av.y,bv.x,acc[1][0]); acc[1][1]=fmaf(av.y,bv.y,acc[1][1]); \
  acc[1][2]=fmaf(av.y,bv.z,acc[1][2]); acc[1][3]=fmaf(av.y,bv.w,acc[1][3]); \
  acc[2][0]=fmaf(av.z,bv.x,acc[2][0]); acc[2][1]=fmaf(av.z,bv.y,acc[2][1]); \
  acc[2][2]=fmaf(av.z,bv.z,acc[2][2]); acc[2][3]=fmaf(av.z,bv.w,acc[2][3]); \
  acc[3][0]=fmaf(av.w,bv.x,acc[3][0]); acc[3][1]=fmaf(av.w,bv.y,acc[3][1]); \
  acc[3][2]=fmaf(av.w,bv.z,acc[3][2]); acc[3][3]=fmaf(av.w,bv.w,acc[3][3]); \
}while(0)

__global__ void k_sentinel(float* out){ out[blockIdx.x*256 + threadIdx.x] = 1.0e6f; }

// prep: f16 weight copies, zero stats accumulators. Runs AFTER k_sel (aliases L).
__global__ __launch_bounds__(256) void k_prep(
    const float* __restrict__ fW1, const float* __restrict__ fW2,
    const float* __restrict__ dW1, const float* __restrict__ eW3,
    f16* __restrict__ fW1h, f16* __restrict__ fW2h, f16* __restrict__ dW1h,
    f16* __restrict__ eW3h, float* __restrict__ accAll)
{
    const int i = blockIdx.x*256 + threadIdx.x;   // 524288 threads
    int f = i >> 9, l = i & 511;
    fW1h[i] = (f16)fW1[(size_t)f*2560 + l];       // x-part only (cols 0..511)
    fW2h[i] = (f16)fW2[i];
    if (i < 8192) { dW1h[i] = (f16)dW1[i]; eW3h[i] = (f16)eW3[i]; }
    if (i < 4096) accAll[i] = 0.f;                // accF(2048)+accD1(128)+accD2(64)+pad
}

// ---------------- c-layers (NT, fp32: feeds argmax) ----------------
__global__ __launch_bounds__(256) void k_gemm_c(
    const float* __restrict__ A, const float* __restrict__ W, float* __restrict__ C,
    int N, int K, const float* __restrict__ sc, const float* __restrict__ sh)
{
    __shared__ __align__(16) float As[16][68];
    __shared__ __align__(16) float Ws[16][68];
    const int n0 = blockIdx.x * 64, m0 = blockIdx.y * 64;
    const int t = threadIdx.x;
    const int kk = t & 15, ri = t >> 4;
    const int tx = t & 15, ty = t >> 4;
    float acc[4][4] = {{0.f,0.f,0.f,0.f},{0.f,0.f,0.f,0.f},{0.f,0.f,0.f,0.f},{0.f,0.f,0.f,0.f}};
    for (int k0 = 0; k0 < K; k0 += 16) {
        float scv = 0.f, shv = 0.f;
        if (sc) { scv = sc[k0+kk]; shv = sh[k0+kk]; }
        #pragma unroll
        for (int mm = 0; mm < 4; ++mm) {
            float v = A[(size_t)(m0 + ri + mm*16) * K + k0 + kk];
            if (sc) v = lrelu(fmaf(v, scv, shv));
            As[kk][ri + mm*16] = v;
        }
        #pragma unroll
        for (int nn = 0; nn < 4; ++nn)
            Ws[kk][ri + nn*16] = W[(size_t)(n0 + ri + nn*16) * K + k0 + kk];
        __syncthreads();
        #pragma unroll
        for (int kq = 0; kq < 16; ++kq) {
            const float4 av = *reinterpret_cast<const float4*>(&As[kq][ty*4]);
            const float4 bv = *reinterpret_cast<const float4*>(&Ws[kq][tx*4]);
            FMA44(av, bv);
        }
        __syncthreads();
    }
    #pragma unroll
    for (int i = 0; i < 4; ++i)
        #pragma unroll
        for (int j = 0; j < 4; ++j)
            C[(size_t)(m0 + ty*4 + i) * N + n0 + tx*4 + j] = acc[i][j];
}

__global__ __launch_bounds__(256) void k_stats2d(const float* __restrict__ buf, int C,
    const float* __restrict__ g, const float* __restrict__ bb,
    float* __restrict__ sc, float* __restrict__ sh)
{
    const int c = blockIdx.x, t = threadIdx.x;
    float v0 = buf[(size_t)t*C + c], v1 = buf[(size_t)(t+256)*C + c];
    __shared__ float ls[256], ls2[256];
    ls[t] = v0 + v1; ls2[t] = v0*v0 + v1*v1;
    __syncthreads();
    for (int off = 128; off; off >>= 1) { if (t < off) { ls[t]+=ls[t+off]; ls2[t]+=ls2[t+off]; } __syncthreads(); }
    if (t == 0) {
        float m = ls[0]*(1.f/512.f);
        float var = fmaxf(ls2[0]*(1.f/512.f) - m*m, 0.f);
        float r = 1.0f / sqrtf(var + 1e-5f);
        float s = g[c]*r; sc[c] = s; sh[c] = bb[c] - m*s;
    }
}

__global__ __launch_bounds__(256) void k_sel(
    const float* __restrict__ Lpre, const float* __restrict__ gumbel,
    const float* __restrict__ sc, const float* __restrict__ sh, int* __restrict__ sel)
{
    const int b = blockIdx.x, hd = threadIdx.x;
    float best = -3.0e38f; int bi = 0;
    #pragma unroll
    for (int cb = 0; cb < 8; ++cb) {
        int c = cb*256 + hd;
        float v = lrelu(fmaf(Lpre[(size_t)b*2048 + c], sc[c], sh[c])) + gumbel[(size_t)b*2048 + c];
        if (v > best) { best = v; bi = cb; }
    }
    sel[b*256 + hd] = bi;
}

__global__ __launch_bounds__(256) void k_val(const float* __restrict__ x,
    float* __restrict__ S, float* __restrict__ S2, float* __restrict__ val)
{
    const int b = blockIdx.x, t = threadIdx.x;
    float v0 = x[b*512 + t], v1 = x[b*512 + t + 256];
    __shared__ float ls[256], ls2[256];
    ls[t] = v0 + v1; ls2[t] = v0*v0 + v1*v1;
    __syncthreads();
    for (int off = 128; off; off >>= 1) { if (t < off) { ls[t]+=ls[t+off]; ls2[t]+=ls2[t+off]; } __syncthreads(); }
    if (t == 0) { float s = ls[0], s2 = ls2[0]; S[b]=s; S2[b]=s2; val[b]=0.5f*(s*s - s2); }
}

__global__ __launch_bounds__(256) void k_e1params(
    const float* __restrict__ S, const float* __restrict__ S2, const float* __restrict__ val,
    const float* __restrict__ eW1, const float* __restrict__ eg1, const float* __restrict__ eb1,
    float* __restrict__ A1, float* __restrict__ C1, float* __restrict__ accs /*384*/)
{
    const int t = threadIdx.x;
    accs[t] = 0.f; if (t < 128) accs[256 + t] = 0.f;
    __shared__ float ls[256], ls2[256];
    float s = 0.f, s2 = 0.f;
    for (int b = t; b < 512; b += 256) {
        float vb = val[b];
        s  += S[b]  + 256.f*vb;
        s2 += S2[b] + 256.f*vb*vb;
    }
    ls[t] = s; ls2[t] = s2; __syncthreads();
    for (int off = 128; off; off >>= 1) { if (t < off) { ls[t]+=ls[t+off]; ls2[t]+=ls2[t+off]; } __syncthreads(); }
    if (t < 32) {
        const float invn = 1.0f/1310720.f;
        float mu = ls[0]*invn;
        float var = fmaxf(ls2[0]*invn - mu*mu, 0.f);
        float w = eW1[t];
        float rs = 1.0f / sqrtf(w*w*var + 1e-5f);
        float a = w * eg1[t] * rs;
        A1[t] = a; C1[t] = eb1[t] - mu*a;
    }
}

// transpose eW2 (64x32)->(32x64)
__global__ void k_wtrans2(const float* __restrict__ eW2, float* __restrict__ eW2T)
{
    const int t = threadIdx.x;
    for (int i = t; i < 2048; i += 256) { int p = i >> 5, o = i & 31; eW2T[o*64 + p] = eW2[i]; }
}

__global__ __launch_bounds__(256) void k_transpose_fz(const float* __restrict__ fW1, float* __restrict__ fzT)
{
    __shared__ float tile[64][65];
    const int z0 = blockIdx.x*64, f0 = blockIdx.y*64;
    const int j = threadIdx.x & 63, i0 = threadIdx.x >> 6;
    #pragma unroll
    for (int ii = 0; ii < 16; ++ii) {
        int fi = i0*16 + ii;
        tile[fi][j] = fW1[(size_t)(f0+fi)*2560 + 512 + z0 + j];
    }
    __syncthreads();
    #pragma unroll
    for (int ii = 0; ii < 16; ++ii) {
        int zi = i0*16 + ii;
        fzT[(size_t)(z0+zi)*1024 + f0 + j] = tile[j][zi];
    }
}

__global__ __launch_bounds__(256) void k_ftot(const float* __restrict__ fzT, float* __restrict__ Ftot)
{
    const int f = blockIdx.x*256 + threadIdx.x;
    float s = 0.f;
    for (int z = 0; z < 2048; ++z) s += fzT[(size_t)z*1024 + f];
    Ftot[f] = s;
}

__global__ __launch_bounds__(256) void k_p1(const float* __restrict__ fzT, const int* __restrict__ sel,
                                            float* __restrict__ P1)
{
    const int b = blockIdx.x, t = threadIdx.x;
    float a0=0.f, a1=0.f, a2=0.f, a3=0.f;
    for (int hd = 0; hd < 256; ++hd) {
        int col = sel[b*256 + hd]*256 + hd;
        const float* r = fzT + (size_t)col*1024;
        a0 += r[t]; a1 += r[t+256]; a2 += r[t+512]; a3 += r[t+768];
    }
    P1[b*1024 + t] = a0; P1[b*1024 + t + 256] = a1; P1[b*1024 + t + 512] = a2; P1[b*1024 + t + 768] = a3;
}

// e2 main points: v2 = eW2 * lrelu(A1*x+C1); write V2x[pt][d] f16. NO stats.
__global__ __launch_bounds__(256) void k_epass2(
    const float* __restrict__ x,
    const float* __restrict__ A1, const float* __restrict__ C1,
    const float* __restrict__ eW2T, f16* __restrict__ V2x)
{
    __shared__ float sW[2048], sA[32], sC[32];
    const int t = threadIdx.x;
    #pragma unroll
    for (int i = 0; i < 8; ++i) sW[t + 256*i] = eW2T[t + 256*i];
    if (t < 32) { sA[t] = A1[t]; sC[t] = C1[t]; }
    __syncthreads();
    const int pt = blockIdx.x*256 + t;
    float phi = x[pt];
    float v2[64];
    #pragma unroll
    for (int p = 0; p < 64; ++p) v2[p] = 0.f;
    for (int o = 0; o < 32; ++o) {
        float t1 = lrelu(fmaf(sA[o], phi, sC[o]));
        #pragma unroll
        for (int p = 0; p < 64; ++p) v2[p] = fmaf(sW[o*64 + p], t1, v2[p]);
    }
    f16* dst = V2x + (size_t)pt*64;
    #pragma unroll
    for (int dd = 0; dd < 64; dd += 8) {
        f16x8 o;
        #pragma unroll
        for (int e = 0; e < 8; ++e) o[e] = (f16)v2[dd+e];
        *reinterpret_cast<f16x8*>(dst + dd) = o;
    }
}

// e2 support points (513): exact f32 v2 -> V2s + weighted stats atomics
__global__ __launch_bounds__(256) void k_esupport2(
    const float* __restrict__ val,
    const float* __restrict__ A1, const float* __restrict__ C1,
    const float* __restrict__ eW2T, float* __restrict__ V2s, float* __restrict__ acc2)
{
    const int idx = blockIdx.x*256 + threadIdx.x;
    if (idx >= 513) return;
    float phi = (idx < 512) ? val[idx] : 0.f;
    float w = (idx < 512) ? 256.f : 917504.f;
    float v2[64];
    #pragma unroll
    for (int p = 0; p < 64; ++p) v2[p] = 0.f;
    for (int o = 0; o < 32; ++o) {
        float t1 = lrelu(fmaf(A1[o], phi, C1[o]));
        #pragma unroll
        for (int p = 0; p < 64; ++p) v2[p] = fmaf(eW2T[o*64 + p], t1, v2[p]);
    }
    for (int p = 0; p < 64; ++p) {
        V2s[idx*64 + p] = v2[p];
        atomicAdd(&acc2[p], w*v2[p]);
        atomicAdd(&acc2[64+p], w*v2[p]*v2[p]);
    }
}

// e2 stats scan over V2x (262144 pts x 64 ch, f16). weight 1.
__global__ __launch_bounds__(256) void k_stats_v2scan(const f16* __restrict__ V2x, float* __restrict__ acc2)
{
    const int t = threadIdx.x;
    const int g = t & 7;
    const int slot = blockIdx.x*32 + (t >> 3);
    float s[8] = {0,0,0,0,0,0,0,0}, s2[8] = {0,0,0,0,0,0,0,0};
    for (int p = slot; p < NXPT; p += 8192) {
        f16x8 v = *reinterpret_cast<const f16x8*>(V2x + (size_t)p*64 + g*8);
        #pragma unroll
        for (int e = 0; e < 8; ++e) { float f = (float)v[e]; s[e] += f; s2[e] += f*f; }
    }
    #pragma unroll
    for (int off = 8; off <= 32; off <<= 1) {
        #pragma unroll
        for (int e = 0; e < 8; ++e) { s[e] += __shfl_xor(s[e], off); s2[e] += __shfl_xor(s2[e], off); }
    }
    if ((t & 63) < 8) {
        int d0 = (t & 7)*8;
        #pragma unroll
        for (int e = 0; e < 8; ++e) {
            atomicAdd(&acc2[d0+e], s[e]);
            atomicAdd(&acc2[64+d0+e], s2[e]);
        }
    }
}

__global__ void k_finalize(const float* __restrict__ acc, int C, float invn,
                           const float* __restrict__ g, const float* __restrict__ bb,
                           float* __restrict__ sc, float* __restrict__ sh)
{
    const int idx = blockIdx.x*blockDim.x + threadIdx.x;
    if (idx < C) {
        float m = acc[idx] * invn;
        float var = fmaxf(acc[C + idx] * invn - m*m, 0.f);
        float r = 1.0f / sqrtf(var + 1e-5f);
        float s = g[idx] * r;
        sc[idx] = s; sh[idx] = bb[idx] - m*s;
    }
}

// MFMA e3: V3xT[b][q][l] = sum_d eW3h[q][d] * f16(lrelu(sc2*V2x[b*512+l][d]+sh2))
__global__ __launch_bounds__(256) void k_mfma_e3(
    const f16* __restrict__ eW3h, const f16* __restrict__ V2x,
    const float* __restrict__ sc2, const float* __restrict__ sh2,
    f16* __restrict__ V3xT)
{
    __shared__ __align__(16) f16 As[128][76];   // eW3 rows q, cols d
    __shared__ __align__(16) f16 Bs[128][76];   // t2 rows point, cols d
    __shared__ float scs[64], shs[64];
    const int b = blockIdx.y, l0 = blockIdx.x * 128;
    const int t = threadIdx.x;
    const int wave = t >> 6, lane = t & 63;
    const int quad = lane >> 4, l16 = lane & 15;
    const int row = t >> 1, half = t & 1;
    if (t < 64) { scs[t] = sc2[t]; shs[t] = sh2[t]; }
    __syncthreads();
    #pragma unroll
    for (int c = 0; c < 4; ++c)
        *reinterpret_cast<f16x8*>(&As[row][half*32 + c*8]) =
            *reinterpret_cast<const f16x8*>(eW3h + row*64 + half*32 + c*8);
    const f16* src = V2x + ((size_t)(b*512 + l0 + row))*64 + half*32;
    #pragma unroll
    for (int c = 0; c < 4; ++c) {
        f16x8 v = *reinterpret_cast<const f16x8*>(src + c*8);
        f16x8 o;
        #pragma unroll
        for (int e = 0; e < 8; ++e) {
            int d = half*32 + c*8 + e;
            o[e] = (f16)lrelu(fmaf(scs[d], (float)v[e], shs[d]));
        }
        *reinterpret_cast<f16x8*>(&Bs[row][half*32 + c*8]) = o;
    }
    __syncthreads();
    f32x4 acc[2][8];
    #pragma unroll
    for (int i = 0; i < 2; ++i)
        #pragma unroll
        for (int j = 0; j < 8; ++j) acc[i][j] = (f32x4){0.f,0.f,0.f,0.f};
    f16x8 a0  = *reinterpret_cast<const f16x8*>(&As[32*wave + l16][quad*8]);
    f16x8 a0b = *reinterpret_cast<const f16x8*>(&As[32*wave + l16][32 + quad*8]);
    f16x8 a1  = *reinterpret_cast<const f16x8*>(&As[32*wave + 16 + l16][quad*8]);
    f16x8 a1b = *reinterpret_cast<const f16x8*>(&As[32*wave + 16 + l16][32 + quad*8]);
    #pragma unroll
    for (int j = 0; j < 8; ++j) {
        f16x8 bj  = *reinterpret_cast<const f16x8*>(&Bs[16*j + l16][quad*8]);
        f16x8 bjb = *reinterpret_cast<const f16x8*>(&Bs[16*j + l16][32 + quad*8]);
        acc[0][j] = __builtin_amdgcn_mfma_f32_16x16x32_f16(a0,  bj,  acc[0][j], 0, 0, 0);
        acc[0][j] = __builtin_amdgcn_mfma_f32_16x16x32_f16(a0b, bjb, acc[0][j], 0, 0, 0);
        acc[1][j] = __builtin_amdgcn_mfma_f32_16x16x32_f16(a1,  bj,  acc[1][j], 0, 0, 0);
        acc[1][j] = __builtin_amdgcn_mfma_f32_16x16x32_f16(a1b, bjb, acc[1][j], 0, 0, 0);
    }
    #pragma unroll
    for (int i = 0; i < 2; ++i) {
        #pragma unroll
        for (int r = 0; r < 4; ++r) {
            int q = 32*wave + 16*i + quad*4 + r;
            #pragma unroll
            for (int j = 0; j < 8; ++j)
                V3xT[((size_t)b*128 + q)*512 + l0 + 16*j + l16] = (f16)acc[i][j][r];
        }
    }
}

// e3 support points: exact f32 path + weighted stats atomics
__global__ __launch_bounds__(256) void k_esupport3(
    const float* __restrict__ V2s, const float* __restrict__ sc2, const float* __restrict__ sh2,
    const float* __restrict__ eW3, float* __restrict__ V3s, float* __restrict__ acc3)
{
    const int idx = blockIdx.x*256 + threadIdx.x;
    if (idx >= 513) return;
    float w = (idx < 512) ? 256.f : 917504.f;
    float t2[64];
    #pragma unroll
    for (int d = 0; d < 64; ++d) t2[d] = lrelu(fmaf(sc2[d], V2s[idx*64 + d], sh2[d]));
    for (int q = 0; q < 128; ++q) {
        float s = 0.f;
        #pragma unroll
        for (int d = 0; d < 64; ++d) s = fmaf(eW3[q*64 + d], t2[d], s);
        V3s[idx*128 + q] = s;
        atomicAdd(&acc3[q], w*s);
        atomicAdd(&acc3[128+q], w*s*s);
    }
}

// e3 stats scan over V3xT (rows (b,q) x 512 f16). weight 1. channel = row & 127.
__global__ __launch_bounds__(256) void k_stats_v3scan(const f16* __restrict__ V3xT, float* __restrict__ acc3)
{
    const int t = threadIdx.x;
    const int wave = t >> 6, lane = t & 63;
    const int rbase = blockIdx.x*32 + wave*8;
    for (int i = 0; i < 8; ++i) {
        int r = rbase + i;
        f16x8 v = *reinterpret_cast<const f16x8*>(V3xT + (size_t)r*512 + lane*8);
        float s = 0.f, s2 = 0.f;
        #pragma unroll
        for (int e = 0; e < 8; ++e) { float f = (float)v[e]; s += f; s2 += f*f; }
        #pragma unroll
        for (int off = 32; off; off >>= 1) { s += __shfl_xor(s, off); s2 += __shfl_xor(s2, off); }
        if (lane == 0) {
            int q = r & 127;
            atomicAdd(&acc3[q], s);
            atomicAdd(&acc3[128+q], s2);
        }
    }
}

__global__ void k_u(const float* __restrict__ V3s, const float* __restrict__ sc3, const float* __restrict__ sh3,
                    float* __restrict__ u1, float* __restrict__ u0)
{
    const int idx = blockIdx.x*256 + threadIdx.x;
    if (idx < 513*128) {
        int i = idx >> 7, q = idx & 127;
        float tv = lrelu(fmaf(sc3[q], V3s[idx], sh3[q]));
        if (i < 512) u1[idx] = tv; else u0[q] = tv;
    }
}

// ---------------- MFMA fw1 (stride 44) ----------------
__global__ __launch_bounds__(256) void k_mfma_fw1T(
    const f16* __restrict__ fW1h, const f16* __restrict__ V3xT,
    const float* __restrict__ sce3, const float* __restrict__ she3,
    const float* __restrict__ u1, const float* __restrict__ u0,
    const float* __restrict__ P1, const float* __restrict__ Ftot,
    f16* __restrict__ out6T)
{
    __shared__ __align__(16) f16 As[128][44];
    __shared__ __align__(16) f16 Bs[128][44];
    const int b = blockIdx.y;
    const int f0 = blockIdx.x * 128;
    const int t = threadIdx.x;
    const int wave = t >> 6, lane = t & 63;
    const int quad = lane >> 4, l16 = lane & 15;
    const int row0 = t >> 2, grp = t & 3;
    const f16* Aa = V3xT + (size_t)b*128*512;
    const float sc0 = sce3[row0], sh0 = she3[row0];
    const float sc1 = sce3[row0+64], sh1 = she3[row0+64];
    f32x4 acc[2][8];
    #pragma unroll
    for (int i = 0; i < 2; ++i)
        #pragma unroll
        for (int j = 0; j < 8; ++j) acc[i][j] = (f32x4){0.f,0.f,0.f,0.f};
    for (int k0 = 0; k0 < 512; k0 += 32) {
        #pragma unroll
        for (int p = 0; p < 2; ++p) {
            const int row = row0 + 64*p;
            const float sc = p ? sc1 : sc0, sh = p ? sh1 : sh0;
            f16x8 v = *reinterpret_cast<const f16x8*>(Aa + (size_t)row*512 + k0 + grp*8);
            f16x8 o;
            #pragma unroll
            for (int e = 0; e < 8; ++e) o[e] = (f16)lrelu(fmaf(sc, (float)v[e], sh));
            *reinterpret_cast<f16x8*>(&As[row][grp*8]) = o;
            f16x8 wv = *reinterpret_cast<const f16x8*>(fW1h + (size_t)(f0+row)*512 + k0 + grp*8);
            *reinterpret_cast<f16x8*>(&Bs[row][grp*8]) = wv;
        }
        __syncthreads();
        f16x8 a0 = *reinterpret_cast<const f16x8*>(&As[32*wave + l16][quad*8]);
        f16x8 a1 = *reinterpret_cast<const f16x8*>(&As[32*wave + 16 + l16][quad*8]);
        #pragma unroll
        for (int j = 0; j < 8; ++j) {
            f16x8 bj = *reinterpret_cast<const f16x8*>(&Bs[16*j + l16][quad*8]);
            acc[0][j] = __builtin_amdgcn_mfma_f32_16x16x32_f16(a0, bj, acc[0][j], 0, 0, 0);
            acc[1][j] = __builtin_amdgcn_mfma_f32_16x16x32_f16(a1, bj, acc[1][j], 0, 0, 0);
        }
        __syncthreads();
    }
    float p1j[8], p0j[8];
    #pragma unroll
    for (int j = 0; j < 8; ++j) {
        int f = f0 + 16*j + l16;
        p1j[j] = P1[b*1024 + f];
        p0j[j] = Ftot[f] - p1j[j];
    }
    #pragma unroll
    for (int i = 0; i < 2; ++i) {
        #pragma unroll
        for (int r = 0; r < 4; ++r) {
            int q = 32*wave + 16*i + quad*4 + r;
            float u1q = u1[b*128 + q], u0q = u0[q];
            #pragma unroll
            for (int j = 0; j < 8; ++j) {
                int f = f0 + 16*j + l16;
                out6T[((size_t)b*128 + q)*1024 + f] = (f16)(acc[i][j][r] + u1q*p1j[j] + u0q*p0j[j]);
            }
        }
    }
}

// ---------------- MFMA fw2 (stride 44) ----------------
__global__ __launch_bounds__(256) void k_mfma_fw2T(
    const f16* __restrict__ fW2h, const f16* __restrict__ out6T,
    const float* __restrict__ scf, const float* __restrict__ shf,
    const float* __restrict__ fbias2, f16* __restrict__ out7)
{
    __shared__ __align__(16) f16 As[128][44];
    __shared__ __align__(16) f16 Bs[128][44];
    const int b = blockIdx.y;
    const int o0 = blockIdx.x * 128;
    const int t = threadIdx.x;
    const int wave = t >> 6, lane = t & 63;
    const int quad = lane >> 4, l16 = lane & 15;
    const int row0 = t >> 2, grp = t & 3;
    const f16* Bb = out6T + (size_t)b*128*1024;
    f32x4 acc[2][8];
    #pragma unroll
    for (int i = 0; i < 2; ++i)
        #pragma unroll
        for (int j = 0; j < 8; ++j) acc[i][j] = (f32x4){0.f,0.f,0.f,0.f};
    for (int k0 = 0; k0 < 1024; k0 += 32) {
        float4 c0 = *reinterpret_cast<const float4*>(scf + k0 + grp*8);
        float4 c1 = *reinterpret_cast<const float4*>(scf + k0 + grp*8 + 4);
        float4 h0 = *reinterpret_cast<const float4*>(shf + k0 + grp*8);
        float4 h1 = *reinterpret_cast<const float4*>(shf + k0 + grp*8 + 4);
        float scv[8] = {c0.x,c0.y,c0.z,c0.w,c1.x,c1.y,c1.z,c1.w};
        float shv[8] = {h0.x,h0.y,h0.z,h0.w,h1.x,h1.y,h1.z,h1.w};
        #pragma unroll
        for (int p = 0; p < 2; ++p) {
            const int row = row0 + 64*p;
            f16x8 wv = *reinterpret_cast<const f16x8*>(fW2h + (size_t)(o0+row)*1024 + k0 + grp*8);
            *reinterpret_cast<f16x8*>(&As[row][grp*8]) = wv;
            f16x8 v = *reinterpret_cast<const f16x8*>(Bb + (size_t)row*1024 + k0 + grp*8);
            f16x8 o;
            #pragma unroll
            for (int e = 0; e < 8; ++e) o[e] = (f16)lrelu(fmaf(scv[e], (float)v[e], shv[e]));
            *reinterpret_cast<f16x8*>(&Bs[row][grp*8]) = o;
        }
        __syncthreads();
        f16x8 a0 = *reinterpret_cast<const f16x8*>(&As[32*wave + l16][quad*8]);
        f16x8 a1 = *reinterpret_cast<const f16x8*>(&As[32*wave + 16 + l16][quad*8]);
        #pragma unroll
        for (int j = 0; j < 8; ++j) {
            f16x8 bj = *reinterpret_cast<const f16x8*>(&Bs[16*j + l16][quad*8]);
            acc[0][j] = __builtin_amdgcn_mfma_f32_16x16x32_f16(a0, bj, acc[0][j], 0, 0, 0);
            acc[1][j] = __builtin_amdgcn_mfma_f32_16x16x32_f16(a1, bj, acc[1][j], 0, 0, 0);
        }
        __syncthreads();
    }
    #pragma unroll
    for (int i = 0; i < 2; ++i) {
        #pragma unroll
        for (int r = 0; r < 4; ++r) {
            int o = o0 + 32*wave + 16*i + quad*4 + r;
            float bias = fbias2[o];
            #pragma unroll
            for (int j = 0; j < 8; ++j) {
                int q = 16*j + l16;
                out7[((size_t)b*512 + o)*128 + q] = (f16)(acc[i][j][r] + bias);
            }
        }
    }
}

// ---------------- MFMA d1 (stride 44) ----------------
__global__ __launch_bounds__(256) void k_mfma_d1(
    const f16* __restrict__ dW1h, const f16* __restrict__ out7, float* __restrict__ d1pre)
{
    __shared__ __align__(16) f16 As[64][44];
    __shared__ __align__(16) f16 Bs[128][44];
    const int b = blockIdx.y, o0 = blockIdx.x * 128;
    const int t = threadIdx.x;
    const int wave = t >> 6, lane = t & 63;
    const int quad = lane >> 4, l16 = lane & 15;
    const int row0 = t >> 2, grp = t & 3;
    const f16* Bb = out7 + (size_t)b*65536;
    f32x4 acc[8];
    #pragma unroll
    for (int j = 0; j < 8; ++j) acc[j] = (f32x4){0.f,0.f,0.f,0.f};
    for (int k0 = 0; k0 < 128; k0 += 32) {
        *reinterpret_cast<f16x8*>(&As[row0][grp*8]) =
            *reinterpret_cast<const f16x8*>(dW1h + row0*128 + k0 + grp*8);
        #pragma unroll
        for (int p = 0; p < 2; ++p) {
            const int row = row0 + 64*p;
            *reinterpret_cast<f16x8*>(&Bs[row][grp*8]) =
                *reinterpret_cast<const f16x8*>(Bb + (size_t)(o0+row)*128 + k0 + grp*8);
        }
        __syncthreads();
        f16x8 a0 = *reinterpret_cast<const f16x8*>(&As[16*wave + l16][quad*8]);
        #pragma unroll
        for (int j = 0; j < 8; ++j) {
            f16x8 bj = *reinterpret_cast<const f16x8*>(&Bs[16*j + l16][quad*8]);
            acc[j] = __builtin_amdgcn_mfma_f32_16x16x32_f16(a0, bj, acc[j], 0, 0, 0);
        }
        __syncthreads();
    }
    #pragma unroll
    for (int r = 0; r < 4; ++r) {
        int d = 16*wave + quad*4 + r;
        #pragma unroll
        for (int j = 0; j < 8; ++j) {
            int o = o0 + 16*j + l16;
            d1pre[(size_t)b*32768 + (size_t)d*512 + o] = acc[j][r];
        }
    }
}

// row-major per-channel (sum,sumsq) partials for f16 [R][1024]; atomicAdd into acc[2048]
__global__ __launch_bounds__(256) void k_stats_rows_f16(
    const f16* __restrict__ buf, float* __restrict__ acc)
{
    const int t = threadIdx.x;
    const int c8 = (t & 127) * 8, rl = t >> 7;
    const size_t r0 = (size_t)blockIdx.x * 256;
    float s[8] = {0,0,0,0,0,0,0,0}, s2[8] = {0,0,0,0,0,0,0,0};
    for (int rr = rl; rr < 256; rr += 2) {
        f16x8 v = *reinterpret_cast<const f16x8*>(buf + (r0 + rr)*1024 + c8);
        #pragma unroll
        for (int e = 0; e < 8; ++e) { float f = (float)v[e]; s[e] += f; s2[e] += f*f; }
    }
    __shared__ float red[128*16];
    if (rl == 1) {
        #pragma unroll
        for (int e = 0; e < 8; ++e) { red[(t&127)*16 + e] = s[e]; red[(t&127)*16 + 8 + e] = s2[e]; }
    }
    __syncthreads();
    if (rl == 0) {
        #pragma unroll
        for (int e = 0; e < 8; ++e) {
            atomicAdd(&acc[c8 + e],        s[e]  + red[t*16 + e]);
            atomicAdd(&acc[1024 + c8 + e], s2[e] + red[t*16 + 8 + e]);
        }
    }
}

// split per-channel stats for f32 buf[b][C][512]
__global__ __launch_bounds__(256) void k_stats_cols_f32(
    const float* __restrict__ buf, int C, float* __restrict__ acc)
{
    const int b = blockIdx.x;
    const int c = blockIdx.y*8 + (threadIdx.x >> 5);
    const int ol = threadIdx.x & 31;
    const float* p = buf + ((size_t)b*C + c)*512;
    float s = 0.f, s2 = 0.f;
    #pragma unroll
    for (int i = 0; i < 16; ++i) { float v = p[ol + 32*i]; s += v; s2 += v*v; }
    #pragma unroll
    for (int off = 16; off; off >>= 1) { s += __shfl_xor(s, off); s2 += __shfl_xor(s2, off); }
    if (ol == 0) { atomicAdd(&acc[c], s); atomicAdd(&acc[C + c], s2); }
}

// d2: C[e,o] = sum_d dW2[e,d] * lrelu(sc*d1pre[b][d][o]+sh)
__global__ __launch_bounds__(128) void k_gemm_d2(
    const float* __restrict__ dW2, const float* __restrict__ d1pre,
    const float* __restrict__ scd, const float* __restrict__ shd, float* __restrict__ d2pre)
{
    __shared__ __align__(16) float As[16][36];
    __shared__ __align__(16) float Bs[16][68];
    const int n0 = blockIdx.x * 64, b = blockIdx.y;
    const int t = threadIdx.x;
    const int kk = t & 15, ri = t >> 4;
    const int qv = t & 63, kh = t >> 6;
    const int tx = t & 15, ty = t >> 4;
    float acc[4][4] = {{0.f,0.f,0.f,0.f},{0.f,0.f,0.f,0.f},{0.f,0.f,0.f,0.f},{0.f,0.f,0.f,0.f}};
    for (int k0 = 0; k0 < 64; k0 += 16) {
        #pragma unroll
        for (int mm = 0; mm < 4; ++mm)
            As[kk][ri + mm*8] = dW2[(ri + mm*8)*64 + k0 + kk];
        #pragma unroll
        for (int ki = 0; ki < 8; ++ki) {
            int d = k0 + kh + ki*2;
            float v = d1pre[(size_t)b*32768 + (size_t)d*512 + n0 + qv];
            Bs[kh + ki*2][qv] = lrelu(fmaf(scd[d], v, shd[d]));
        }
        __syncthreads();
        #pragma unroll
        for (int kq = 0; kq < 16; ++kq) {
            const float4 av = *reinterpret_cast<const float4*>(&As[kq][ty*4]);
            const float4 bv = *reinterpret_cast<const float4*>(&Bs[kq][tx*4]);
            FMA44(av, bv);
        }
        __syncthreads();
    }
    #pragma unroll
    for (int i = 0; i < 4; ++i)
        #pragma unroll
        for (int j = 0; j < 4; ++j)
            d2pre[(size_t)b*16384 + (size_t)(ty*4 + i)*512 + n0 + tx*4 + j] = acc[i][j];
}

__global__ __launch_bounds__(256) void k_d3(
    const float* __restrict__ d2pre, const float* __restrict__ dW3,
    const float* __restrict__ sce, const float* __restrict__ she,
    const float* __restrict__ dbias3, float* __restrict__ out)
{
    const int idx = blockIdx.x*256 + threadIdx.x;
    const int b = idx >> 9, o = idx & 511;
    float s = dbias3[0];
    for (int e = 0; e < 32; ++e) {
        float v = d2pre[(size_t)b*16384 + e*512 + o];
        s = fmaf(dW3[e], lrelu(fmaf(v, sce[e], she[e])), s);
    }
    out[idx] = s;
}

extern "C" void kernel_launch(void* const* d_in, const int* in_sizes, int n_in,
                              void* d_out, int out_size, void* d_ws, size_t ws_size,
                              hipStream_t stream)
{
    (void)in_sizes; (void)n_in; (void)out_size;
    const float* x      = (const float*)d_in[0];
    const float* gumbel = (const float*)d_in[1];
    const float* cW1 = (const float*)d_in[2];
    const float* cg1 = (const float*)d_in[3];
    const float* cb1 = (const float*)d_in[4];
    const float* cW2 = (const float*)d_in[5];
    const float* cg2 = (const float*)d_in[6];
    const float* cb2 = (const float*)d_in[7];
    const float* cW3 = (const float*)d_in[8];
    const float* cg3 = (const float*)d_in[9];
    const float* cb3 = (const float*)d_in[10];
    const float* eW1 = (const float*)d_in[11];
    const float* eg1 = (const float*)d_in[12];
    const float* eb1 = (const float*)d_in[13];
    const float* eW2 = (const float*)d_in[14];
    const float* eg2 = (const float*)d_in[15];
    const float* eb2 = (const float*)d_in[16];
    const float* eW3 = (const float*)d_in[17];
    const float* eg3 = (const float*)d_in[18];
    const float* eb3 = (const float*)d_in[19];
    const float* fW1 = (const float*)d_in[20];
    const float* fg1 = (const float*)d_in[21];
    const float* fb1 = (const float*)d_in[22];
    const float* fW2 = (const float*)d_in[23];
    const float* fbias2 = (const float*)d_in[24];
    const float* dW1 = (const float*)d_in[25];
    const float* dg1 = (const float*)d_in[26];
    const float* db1 = (const float*)d_in[27];
    const float* dW2 = (const float*)d_in[28];
    const float* dg2 = (const float*)d_in[29];
    const float* db2 = (const float*)d_in[30];
    const float* dW3 = (const float*)d_in[31];
    const float* dbias3 = (const float*)d_in[32];
    float* out = (float*)d_out;
    float* ws  = (float*)d_ws;

    if (ws_size < O_END * sizeof(float)) {
        k_sentinel<<<1024,256,0,stream>>>(out);
        return;
    }

    float* H1  = ws + O_H1;
    float* H2  = ws + O_H2;
    float* L   = ws + O_L;
    int*   sel = (int*)(ws + O_SEL);
    float* S   = ws + O_S;
    float* S2  = ws + O_S2;
    float* val = ws + O_VAL;
    float* prm = ws + O_PRM;
    f16*   fW1h= (f16*)(ws + O_FW1H);
    f16*   fW2h= (f16*)(ws + O_FW2H);
    float* accF= ws + O_ACCF;
    float* accD1= ws + O_ACCD1;
    float* accD2= ws + O_ACCD2;
    f16*   dW1h= (f16*)(ws + O_DW1H);
    f16*   eW3h= (f16*)(ws + O_EW3H);
    float* V2s = ws + O_V2SS;
    float* u1  = ws + O_U1;
    float* P1  = ws + O_P1;
    float* fzT = ws + O_FZT;
    float* V3s = ws + O_V3S;
    f16*   V3xT= (f16*)(ws + O_BIG1);
    f16*   out7= (f16*)(ws + O_BIG1);   // aliases V3xT (dead after fw1)
    f16*   out6T=(f16*)(ws + O_BIG2);
    f16*   V2x = (f16*)(ws + O_BIG2);   // aliases out6T (V2x dead before fw1 writes out6T)
    float* d1p = ws + O_D1;             // aliases out6T (dead after fw2)
    float* d2p = ws + O_D2;

    const float invN_e = 1.0f/1310720.f;

    // ---- c-path (deterministic fp32; feeds argmax) ----
    k_gemm_c<<<dim3(16,8),256,0,stream>>>(x,  cW1, H1, 1024, 512,  nullptr,     nullptr);
    k_stats2d<<<1024,256,0,stream>>>(H1, 1024, cg1, cb1, prm+P_SC1, prm+P_SH1);
    k_gemm_c<<<dim3(16,8),256,0,stream>>>(H1, cW2, H2, 1024, 1024, prm+P_SC1, prm+P_SH1);
    k_stats2d<<<1024,256,0,stream>>>(H2, 1024, cg2, cb2, prm+P_SC2, prm+P_SH2);
    k_gemm_c<<<dim3(32,8),256,0,stream>>>(H2, cW3, L,  2048, 1024, prm+P_SC2, prm+P_SH2);
    k_stats2d<<<2048,256,0,stream>>>(L, 2048, cg3, cb3, prm+P_SC3, prm+P_SH3);
    k_sel<<<512,256,0,stream>>>(L, gumbel, prm+P_SC3, prm+P_SH3, sel);

    // ---- weight prep (overwrites L region) + selection-derived helpers ----
    k_prep<<<2048,256,0,stream>>>(fW1, fW2, dW1, eW3, fW1h, fW2h, dW1h, eW3h, accF);
    k_val<<<512,256,0,stream>>>(x, S, S2, val);
    k_e1params<<<1,256,0,stream>>>(S, S2, val, eW1, eg1, eb1, prm+P_A1, prm+P_C1, prm+P_ACC2);
    k_transpose_fz<<<dim3(32,16),256,0,stream>>>(fW1, fzT);
    k_wtrans2<<<1,256,0,stream>>>(eW2, prm+P_EW2T);
    k_ftot<<<4,256,0,stream>>>(fzT, prm+P_FTOT);
    k_p1<<<512,256,0,stream>>>(fzT, sel, P1);

    // ---- e-path ----
    k_epass2<<<1024,256,0,stream>>>(x, prm+P_A1, prm+P_C1, prm+P_EW2T, V2x);
    k_esupport2<<<3,256,0,stream>>>(val, prm+P_A1, prm+P_C1, prm+P_EW2T, V2s, prm+P_ACC2);
    k_stats_v2scan<<<256,256,0,stream>>>(V2x, prm+P_ACC2);
    k_finalize<<<1,256,0,stream>>>(prm+P_ACC2, 64, invN_e, eg2, eb2, prm+P_SCE2, prm+P_SHE2);
    k_mfma_e3<<<dim3(4,512),256,0,stream>>>(eW3h, V2x, prm+P_SCE2, prm+P_SHE2, V3xT);
    k_esupport3<<<3,256,0,stream>>>(V2s, prm+P_SCE2, prm+P_SHE2, eW3, V3s, prm+P_ACC3);
    k_stats_v3scan<<<2048,256,0,stream>>>(V3xT, prm+P_ACC3);
    k_finalize<<<1,256,0,stream>>>(prm+P_ACC3, 128, invN_e, eg3, eb3, prm+P_SCE3, prm+P_SHE3);
    k_u<<<257,256,0,stream>>>(V3s, prm+P_SCE3, prm+P_SHE3, u1, prm+P_U0);

    // ---- f-path (MFMA f16) ----
    k_mfma_fw1T<<<dim3(8,512),256,0,stream>>>(fW1h, V3xT, prm+P_SCE3, prm+P_SHE3,
                                              u1, prm+P_U0, P1, prm+P_FTOT, out6T);
    k_stats_rows_f16<<<256,256,0,stream>>>(out6T, accF);
    k_finalize<<<4,256,0,stream>>>(accF, 1024, 1.0f/65536.f, fg1, fb1, prm+P_SCF1, prm+P_SHF1);
    k_mfma_fw2T<<<dim3(4,512),256,0,stream>>>(fW2h, out6T, prm+P_SCF1, prm+P_SHF1, fbias2, out7);

    // ---- d-path ----
    k_mfma_d1<<<dim3(4,512),256,0,stream>>>(dW1h, out7, d1p);
    k_stats_cols_f32<<<dim3(512,8),256,0,stream>>>(d1p, 64, accD1);
    k_finalize<<<1,256,0,stream>>>(accD1, 64, 1.0f/262144.f, dg1, db1, prm+P_SCD1, prm+P_SHD1);
    k_gemm_d2<<<dim3(8,512),128,0,stream>>>(dW2, d1p, prm+P_SCD1, prm+P_SHD1, d2p);
    k_stats_cols_f32<<<dim3(512,4),256,0,stream>>>(d2p, 32, accD2);
    k_finalize<<<1,256,0,stream>>>(accD2, 32, 1.0f/262144.f, dg2, db2, prm+P_SCD2, prm+P_SHD2);
    k_d3<<<1024,256,0,stream>>>(d2p, dW3, prm+P_SCD2, prm+P_SHD2, dbias3, out);
}

// Round 7
// 1231.500 us; speedup vs baseline: 1.9459x; 1.9459x over previous
//
#include <hip/hip_runtime.h>
#include <cstddef>

#define DEV __device__ __forceinline__
DEV float lrelu(float x){ return x >= 0.0f ? x : 0.2f*x; }
typedef _Float16 f16;
typedef _Float16 f16x8 __attribute__((ext_vector_type(8)));
typedef float f32x4 __attribute__((ext_vector_type(4)));

// Problem dims: B=512, IN=512, CB=8, HD=256, CH=2048, CC=2560, EXP=128, FC1=1024, OUT=512
constexpr int NXPT = 512*512;     // dense support points (b,l<512)

// ---------------- workspace layout (float offsets) ----------------
constexpr size_t O_H1  = 0;                       // 512x1024 f32
constexpr size_t O_H2  = O_H1 + 512*1024;         // 512x1024 f32
constexpr size_t O_L   = O_H2 + 512*1024;         // 512x2048 f32 (c3 logits; dead after k_sel)
constexpr size_t O_SEL = O_L  + 512*2048;         // int32 512x256
constexpr size_t O_S   = O_SEL + 512*256;
constexpr size_t O_S2  = O_S + 512;
constexpr size_t O_VAL = O_S2 + 512;
constexpr size_t O_PRM = O_VAL + 512;
// params sub-offsets (within PRM)
constexpr size_t P_SC1=0, P_SH1=1024, P_SC2=2048, P_SH2=3072, P_SC3=4096, P_SH3=6144;
constexpr size_t P_A1=8192, P_C1=8224, P_EW2T=8256 /*2048*/;
constexpr size_t P_ACC2=18496 /*128*/, P_ACC3=18624 /*256*/;
constexpr size_t P_SCE2=18880, P_SHE2=18944, P_SCE3=19008, P_SHE3=19136;
constexpr size_t P_U0=19264 /*128*/, P_FTOT=19392 /*1024*/;
constexpr size_t P_SCF1=20416, P_SHF1=21440;
constexpr size_t P_SCD1=22464, P_SHD1=22528, P_SCD2=22592, P_SHD2=22624;
constexpr size_t PRM_SIZE = 32768;
// weight copies + stats accumulators + V2s ALIAS the dead L buffer (written after k_sel)
constexpr size_t O_FW1H = O_L;                    // f16 1024x512   (262144 floats)
constexpr size_t O_FW2H = O_L + 262144;           // f16 512x1024   (262144 floats)
constexpr size_t O_ACCF = O_L + 524288;           // f32 2048
constexpr size_t O_ACCD1= O_ACCF + 2048;          // f32 128
constexpr size_t O_ACCD2= O_ACCD1 + 128;          // f32 64
constexpr size_t O_DW1H = O_L + 528384;           // f16 64x128  (4096 floats)
constexpr size_t O_EW3H = O_L + 532480;           // f16 128x64  (4096 floats)
constexpr size_t O_V2SS = O_L + 536576;           // f32 513x64  (32832 floats)
constexpr size_t O_U1  = O_PRM + PRM_SIZE;        // 512x128 f32
constexpr size_t O_P1  = O_U1 + 512*128;          // 512x1024 f32
constexpr size_t O_FZT = O_P1 + 512*1024;         // 2048x1024 f32 (fW1 z-part transposed)
constexpr size_t O_V3S = O_FZT + (size_t)2048*1024;   // 513x128 f32
constexpr size_t O_BIG1= O_V3S + 513*128;             // f16 512*128*512  (V3xT, later out7)
constexpr size_t O_BIG2= O_BIG1 + (size_t)512*512*128/2; // f16 512*128*1024 (out6T); V2x + d1p/d2p alias
constexpr size_t O_D1  = O_BIG2;                      // f32 512*64*512 (aliases out6T)
constexpr size_t O_D2  = O_BIG2 + (size_t)512*64*512; // f32 512*32*512
constexpr size_t O_END = O_BIG2 + (size_t)512*1024*128/2;   // ~211 MB

#define FMA44(av,bv) do{ \
  acc[0][0]=fmaf(av.x,bv.x,acc[0][0]); acc[0][1]=fmaf(av.x,bv.y,acc[0][1]); \
  acc[0][2]=fmaf(av.x,bv.z,acc[0][2]); acc[0][3]=fmaf(av.x,bv.w,acc[0][3]); \
  acc[1][0]=fmaf(av.y,bv.x,acc[1][0]); acc[1][1]=fmaf(av.y,bv.y,acc[1][1]); \
  acc[1][2]=fmaf(av.y,bv.z,acc[1][2]); acc[1][3]=fmaf(av.y,bv.w,acc[1][3]); \
  acc[2][0]=fmaf(av.z,bv.x,acc[2][0]); acc[2][1]=fmaf(av.z,bv.y,acc[2][1]); \
  acc[2][2]=fmaf(av.z,bv.z,acc[2][2]); acc[2][3]=fmaf(av.z,bv.w,acc[2][3]); \
  acc[3][0]=fmaf(av.w,bv.x,acc[3][0]); acc[3][1]=fmaf(av.w,bv.y,acc[3][1]); \
  acc[3][2]=fmaf(av.w,bv.z,acc[3][2]); acc[3][3]=fmaf(av.w,bv.w,acc[3][3]); \
}while(0)

__global__ void k_sentinel(float* out){ out[blockIdx.x*256 + threadIdx.x] = 1.0e6f; }

// prep: f16 weight copies, zero stats accumulators. Runs AFTER k_sel (aliases L).
__global__ __launch_bounds__(256) void k_prep(
    const float* __restrict__ fW1, const float* __restrict__ fW2,
    const float* __restrict__ dW1, const float* __restrict__ eW3,
    f16* __restrict__ fW1h, f16* __restrict__ fW2h, f16* __restrict__ dW1h,
    f16* __restrict__ eW3h, float* __restrict__ accAll)
{
    const int i = blockIdx.x*256 + threadIdx.x;   // 524288 threads
    int f = i >> 9, l = i & 511;
    fW1h[i] = (f16)fW1[(size_t)f*2560 + l];       // x-part only (cols 0..511)
    fW2h[i] = (f16)fW2[i];
    if (i < 8192) { dW1h[i] = (f16)dW1[i]; eW3h[i] = (f16)eW3[i]; }
    if (i < 4096) accAll[i] = 0.f;                // accF(2048)+accD1(128)+accD2(64)+pad
}

// ---------------- c-layers (NT, fp32: feeds argmax) ----------------
__global__ __launch_bounds__(256) void k_gemm_c(
    const float* __restrict__ A, const float* __restrict__ W, float* __restrict__ C,
    int N, int K, const float* __restrict__ sc, const float* __restrict__ sh)
{
    __shared__ __align__(16) float As[16][68];
    __shared__ __align__(16) float Ws[16][68];
    const int n0 = blockIdx.x * 64, m0 = blockIdx.y * 64;
    const int t = threadIdx.x;
    const int kk = t & 15, ri = t >> 4;
    const int tx = t & 15, ty = t >> 4;
    float acc[4][4] = {{0.f,0.f,0.f,0.f},{0.f,0.f,0.f,0.f},{0.f,0.f,0.f,0.f},{0.f,0.f,0.f,0.f}};
    for (int k0 = 0; k0 < K; k0 += 16) {
        float scv = 0.f, shv = 0.f;
        if (sc) { scv = sc[k0+kk]; shv = sh[k0+kk]; }
        #pragma unroll
        for (int mm = 0; mm < 4; ++mm) {
            float v = A[(size_t)(m0 + ri + mm*16) * K + k0 + kk];
            if (sc) v = lrelu(fmaf(v, scv, shv));
            As[kk][ri + mm*16] = v;
        }
        #pragma unroll
        for (int nn = 0; nn < 4; ++nn)
            Ws[kk][ri + nn*16] = W[(size_t)(n0 + ri + nn*16) * K + k0 + kk];
        __syncthreads();
        #pragma unroll
        for (int kq = 0; kq < 16; ++kq) {
            const float4 av = *reinterpret_cast<const float4*>(&As[kq][ty*4]);
            const float4 bv = *reinterpret_cast<const float4*>(&Ws[kq][tx*4]);
            FMA44(av, bv);
        }
        __syncthreads();
    }
    #pragma unroll
    for (int i = 0; i < 4; ++i)
        #pragma unroll
        for (int j = 0; j < 4; ++j)
            C[(size_t)(m0 + ty*4 + i) * N + n0 + tx*4 + j] = acc[i][j];
}

__global__ __launch_bounds__(256) void k_stats2d(const float* __restrict__ buf, int C,
    const float* __restrict__ g, const float* __restrict__ bb,
    float* __restrict__ sc, float* __restrict__ sh)
{
    const int c = blockIdx.x, t = threadIdx.x;
    float v0 = buf[(size_t)t*C + c], v1 = buf[(size_t)(t+256)*C + c];
    __shared__ float ls[256], ls2[256];
    ls[t] = v0 + v1; ls2[t] = v0*v0 + v1*v1;
    __syncthreads();
    for (int off = 128; off; off >>= 1) { if (t < off) { ls[t]+=ls[t+off]; ls2[t]+=ls2[t+off]; } __syncthreads(); }
    if (t == 0) {
        float m = ls[0]*(1.f/512.f);
        float var = fmaxf(ls2[0]*(1.f/512.f) - m*m, 0.f);
        float r = 1.0f / sqrtf(var + 1e-5f);
        float s = g[c]*r; sc[c] = s; sh[c] = bb[c] - m*s;
    }
}

__global__ __launch_bounds__(256) void k_sel(
    const float* __restrict__ Lpre, const float* __restrict__ gumbel,
    const float* __restrict__ sc, const float* __restrict__ sh, int* __restrict__ sel)
{
    const int b = blockIdx.x, hd = threadIdx.x;
    float best = -3.0e38f; int bi = 0;
    #pragma unroll
    for (int cb = 0; cb < 8; ++cb) {
        int c = cb*256 + hd;
        float v = lrelu(fmaf(Lpre[(size_t)b*2048 + c], sc[c], sh[c])) + gumbel[(size_t)b*2048 + c];
        if (v > best) { best = v; bi = cb; }
    }
    sel[b*256 + hd] = bi;
}

__global__ __launch_bounds__(256) void k_val(const float* __restrict__ x,
    float* __restrict__ S, float* __restrict__ S2, float* __restrict__ val)
{
    const int b = blockIdx.x, t = threadIdx.x;
    float v0 = x[b*512 + t], v1 = x[b*512 + t + 256];
    __shared__ float ls[256], ls2[256];
    ls[t] = v0 + v1; ls2[t] = v0*v0 + v1*v1;
    __syncthreads();
    for (int off = 128; off; off >>= 1) { if (t < off) { ls[t]+=ls[t+off]; ls2[t]+=ls2[t+off]; } __syncthreads(); }
    if (t == 0) { float s = ls[0], s2 = ls2[0]; S[b]=s; S2[b]=s2; val[b]=0.5f*(s*s - s2); }
}

__global__ __launch_bounds__(256) void k_e1params(
    const float* __restrict__ S, const float* __restrict__ S2, const float* __restrict__ val,
    const float* __restrict__ eW1, const float* __restrict__ eg1, const float* __restrict__ eb1,
    float* __restrict__ A1, float* __restrict__ C1, float* __restrict__ accs /*384*/)
{
    const int t = threadIdx.x;
    accs[t] = 0.f; if (t < 128) accs[256 + t] = 0.f;
    __shared__ float ls[256], ls2[256];
    float s = 0.f, s2 = 0.f;
    for (int b = t; b < 512; b += 256) {
        float vb = val[b];
        s  += S[b]  + 256.f*vb;
        s2 += S2[b] + 256.f*vb*vb;
    }
    ls[t] = s; ls2[t] = s2; __syncthreads();
    for (int off = 128; off; off >>= 1) { if (t < off) { ls[t]+=ls[t+off]; ls2[t]+=ls2[t+off]; } __syncthreads(); }
    if (t < 32) {
        const float invn = 1.0f/1310720.f;
        float mu = ls[0]*invn;
        float var = fmaxf(ls2[0]*invn - mu*mu, 0.f);
        float w = eW1[t];
        float rs = 1.0f / sqrtf(w*w*var + 1e-5f);
        float a = w * eg1[t] * rs;
        A1[t] = a; C1[t] = eb1[t] - mu*a;
    }
}

// transpose eW2 (64x32)->(32x64)
__global__ void k_wtrans2(const float* __restrict__ eW2, float* __restrict__ eW2T)
{
    const int t = threadIdx.x;
    for (int i = t; i < 2048; i += 256) { int p = i >> 5, o = i & 31; eW2T[o*64 + p] = eW2[i]; }
}

__global__ __launch_bounds__(256) void k_transpose_fz(const float* __restrict__ fW1, float* __restrict__ fzT)
{
    __shared__ float tile[64][65];
    const int z0 = blockIdx.x*64, f0 = blockIdx.y*64;
    const int j = threadIdx.x & 63, i0 = threadIdx.x >> 6;
    #pragma unroll
    for (int ii = 0; ii < 16; ++ii) {
        int fi = i0*16 + ii;
        tile[fi][j] = fW1[(size_t)(f0+fi)*2560 + 512 + z0 + j];
    }
    __syncthreads();
    #pragma unroll
    for (int ii = 0; ii < 16; ++ii) {
        int zi = i0*16 + ii;
        fzT[(size_t)(z0+zi)*1024 + f0 + j] = tile[j][zi];
    }
}

__global__ __launch_bounds__(256) void k_ftot(const float* __restrict__ fzT, float* __restrict__ Ftot)
{
    const int f = blockIdx.x*256 + threadIdx.x;
    float s = 0.f;
    for (int z = 0; z < 2048; ++z) s += fzT[(size_t)z*1024 + f];
    Ftot[f] = s;
}

__global__ __launch_bounds__(256) void k_p1(const float* __restrict__ fzT, const int* __restrict__ sel,
                                            float* __restrict__ P1)
{
    const int b = blockIdx.x, t = threadIdx.x;
    float a0=0.f, a1=0.f, a2=0.f, a3=0.f;
    for (int hd = 0; hd < 256; ++hd) {
        int col = sel[b*256 + hd]*256 + hd;
        const float* r = fzT + (size_t)col*1024;
        a0 += r[t]; a1 += r[t+256]; a2 += r[t+512]; a3 += r[t+768];
    }
    P1[b*1024 + t] = a0; P1[b*1024 + t + 256] = a1; P1[b*1024 + t + 512] = a2; P1[b*1024 + t + 768] = a3;
}

// e2 main points: v2 = eW2 * lrelu(A1*x+C1); write V2x[pt][d] f16. NO stats.
__global__ __launch_bounds__(256) void k_epass2(
    const float* __restrict__ x,
    const float* __restrict__ A1, const float* __restrict__ C1,
    const float* __restrict__ eW2T, f16* __restrict__ V2x)
{
    __shared__ float sW[2048], sA[32], sC[32];
    const int t = threadIdx.x;
    #pragma unroll
    for (int i = 0; i < 8; ++i) sW[t + 256*i] = eW2T[t + 256*i];
    if (t < 32) { sA[t] = A1[t]; sC[t] = C1[t]; }
    __syncthreads();
    const int pt = blockIdx.x*256 + t;
    float phi = x[pt];
    float v2[64];
    #pragma unroll
    for (int p = 0; p < 64; ++p) v2[p] = 0.f;
    for (int o = 0; o < 32; ++o) {
        float t1 = lrelu(fmaf(sA[o], phi, sC[o]));
        #pragma unroll
        for (int p = 0; p < 64; ++p) v2[p] = fmaf(sW[o*64 + p], t1, v2[p]);
    }
    f16* dst = V2x + (size_t)pt*64;
    #pragma unroll
    for (int dd = 0; dd < 64; dd += 8) {
        f16x8 o;
        #pragma unroll
        for (int e = 0; e < 8; ++e) o[e] = (f16)v2[dd+e];
        *reinterpret_cast<f16x8*>(dst + dd) = o;
    }
}

// e2 support points: grid 513 x 64 threads; one thread per output channel; no atomics
__global__ __launch_bounds__(64) void k_esupport2(
    const float* __restrict__ val,
    const float* __restrict__ A1, const float* __restrict__ C1,
    const float* __restrict__ eW2T, float* __restrict__ V2s)
{
    const int idx = blockIdx.x, d = threadIdx.x;
    float phi = (idx < 512) ? val[idx] : 0.f;
    __shared__ float t1s[32];
    if (d < 32) t1s[d] = lrelu(fmaf(A1[d], phi, C1[d]));
    __syncthreads();
    float s = 0.f;
    #pragma unroll
    for (int o = 0; o < 32; ++o) s = fmaf(eW2T[o*64 + d], t1s[o], s);
    V2s[idx*64 + d] = s;
}

// weighted column stats over V[513][C]: grid C blocks x 64 threads; 2 atomics/block
__global__ __launch_bounds__(64) void k_wstats(
    const float* __restrict__ V, int C, float* __restrict__ acc)
{
    const int c = blockIdx.x, lane = threadIdx.x;
    float s = 0.f, s2 = 0.f;
    for (int i = lane; i < 513; i += 64) {
        float w = (i < 512) ? 256.f : 917504.f;
        float v = V[(size_t)i*C + c];
        s += w*v; s2 += w*v*v;
    }
    #pragma unroll
    for (int off = 32; off; off >>= 1) { s += __shfl_xor(s, off); s2 += __shfl_xor(s2, off); }
    if (lane == 0) { atomicAdd(&acc[c], s); atomicAdd(&acc[C + c], s2); }
}

// e2 stats scan over V2x (262144 pts x 64 ch, f16). 64 blocks; LDS reduce; 128 atomics/block.
__global__ __launch_bounds__(256) void k_stats_v2scan(const f16* __restrict__ V2x, float* __restrict__ acc2)
{
    const int t = threadIdx.x;
    const int wave = t >> 6, lane = t & 63;
    const int g = t & 7;
    const int slot = blockIdx.x*32 + (t >> 3);
    float s[8] = {0,0,0,0,0,0,0,0}, s2[8] = {0,0,0,0,0,0,0,0};
    for (int p = slot; p < NXPT; p += 2048) {
        f16x8 v = *reinterpret_cast<const f16x8*>(V2x + (size_t)p*64 + g*8);
        #pragma unroll
        for (int e = 0; e < 8; ++e) { float f = (float)v[e]; s[e] += f; s2[e] += f*f; }
    }
    #pragma unroll
    for (int off = 8; off <= 32; off <<= 1) {
        #pragma unroll
        for (int e = 0; e < 8; ++e) { s[e] += __shfl_xor(s[e], off); s2[e] += __shfl_xor(s2[e], off); }
    }
    __shared__ float red[4*128];
    if (lane < 8) {
        #pragma unroll
        for (int e = 0; e < 8; ++e) {
            red[wave*128 + lane*16 + e]     = s[e];
            red[wave*128 + lane*16 + 8 + e] = s2[e];
        }
    }
    __syncthreads();
    if (t < 128) {
        float v = red[t] + red[128 + t] + red[256 + t] + red[384 + t];
        int gg = t >> 4, k = t & 15;
        if (k < 8) atomicAdd(&acc2[gg*8 + k], v);
        else       atomicAdd(&acc2[64 + gg*8 + (k - 8)], v);
    }
}

__global__ void k_finalize(const float* __restrict__ acc, int C, float invn,
                           const float* __restrict__ g, const float* __restrict__ bb,
                           float* __restrict__ sc, float* __restrict__ sh)
{
    const int idx = blockIdx.x*blockDim.x + threadIdx.x;
    if (idx < C) {
        float m = acc[idx] * invn;
        float var = fmaxf(acc[C + idx] * invn - m*m, 0.f);
        float r = 1.0f / sqrtf(var + 1e-5f);
        float s = g[idx] * r;
        sc[idx] = s; sh[idx] = bb[idx] - m*s;
    }
}

// MFMA e3: V3xT[b][q][l] = sum_d eW3h[q][d] * f16(lrelu(sc2*V2x[b*512+l][d]+sh2))
__global__ __launch_bounds__(256) void k_mfma_e3(
    const f16* __restrict__ eW3h, const f16* __restrict__ V2x,
    const float* __restrict__ sc2, const float* __restrict__ sh2,
    f16* __restrict__ V3xT)
{
    __shared__ __align__(16) f16 As[128][76];   // eW3 rows q, cols d
    __shared__ __align__(16) f16 Bs[128][76];   // t2 rows point, cols d
    __shared__ float scs[64], shs[64];
    const int b = blockIdx.y, l0 = blockIdx.x * 128;
    const int t = threadIdx.x;
    const int wave = t >> 6, lane = t & 63;
    const int quad = lane >> 4, l16 = lane & 15;
    const int row = t >> 1, half = t & 1;
    if (t < 64) { scs[t] = sc2[t]; shs[t] = sh2[t]; }
    __syncthreads();
    #pragma unroll
    for (int c = 0; c < 4; ++c)
        *reinterpret_cast<f16x8*>(&As[row][half*32 + c*8]) =
            *reinterpret_cast<const f16x8*>(eW3h + row*64 + half*32 + c*8);
    const f16* src = V2x + ((size_t)(b*512 + l0 + row))*64 + half*32;
    #pragma unroll
    for (int c = 0; c < 4; ++c) {
        f16x8 v = *reinterpret_cast<const f16x8*>(src + c*8);
        f16x8 o;
        #pragma unroll
        for (int e = 0; e < 8; ++e) {
            int d = half*32 + c*8 + e;
            o[e] = (f16)lrelu(fmaf(scs[d], (float)v[e], shs[d]));
        }
        *reinterpret_cast<f16x8*>(&Bs[row][half*32 + c*8]) = o;
    }
    __syncthreads();
    f32x4 acc[2][8];
    #pragma unroll
    for (int i = 0; i < 2; ++i)
        #pragma unroll
        for (int j = 0; j < 8; ++j) acc[i][j] = (f32x4){0.f,0.f,0.f,0.f};
    f16x8 a0  = *reinterpret_cast<const f16x8*>(&As[32*wave + l16][quad*8]);
    f16x8 a0b = *reinterpret_cast<const f16x8*>(&As[32*wave + l16][32 + quad*8]);
    f16x8 a1  = *reinterpret_cast<const f16x8*>(&As[32*wave + 16 + l16][quad*8]);
    f16x8 a1b = *reinterpret_cast<const f16x8*>(&As[32*wave + 16 + l16][32 + quad*8]);
    #pragma unroll
    for (int j = 0; j < 8; ++j) {
        f16x8 bj  = *reinterpret_cast<const f16x8*>(&Bs[16*j + l16][quad*8]);
        f16x8 bjb = *reinterpret_cast<const f16x8*>(&Bs[16*j + l16][32 + quad*8]);
        acc[0][j] = __builtin_amdgcn_mfma_f32_16x16x32_f16(a0,  bj,  acc[0][j], 0, 0, 0);
        acc[0][j] = __builtin_amdgcn_mfma_f32_16x16x32_f16(a0b, bjb, acc[0][j], 0, 0, 0);
        acc[1][j] = __builtin_amdgcn_mfma_f32_16x16x32_f16(a1,  bj,  acc[1][j], 0, 0, 0);
        acc[1][j] = __builtin_amdgcn_mfma_f32_16x16x32_f16(a1b, bjb, acc[1][j], 0, 0, 0);
    }
    #pragma unroll
    for (int i = 0; i < 2; ++i) {
        #pragma unroll
        for (int r = 0; r < 4; ++r) {
            int q = 32*wave + 16*i + quad*4 + r;
            #pragma unroll
            for (int j = 0; j < 8; ++j)
                V3xT[((size_t)b*128 + q)*512 + l0 + 16*j + l16] = (f16)acc[i][j][r];
        }
    }
}

// e3 support points: grid 513 x 128 threads; one thread per output q; no atomics
__global__ __launch_bounds__(128) void k_esupport3(
    const float* __restrict__ V2s, const float* __restrict__ sc2, const float* __restrict__ sh2,
    const float* __restrict__ eW3, float* __restrict__ V3s)
{
    const int idx = blockIdx.x, q = threadIdx.x;
    __shared__ float t2s[64];
    if (q < 64) t2s[q] = lrelu(fmaf(sc2[q], V2s[idx*64 + q], sh2[q]));
    __syncthreads();
    float s = 0.f;
    #pragma unroll
    for (int d = 0; d < 64; ++d) s = fmaf(eW3[q*64 + d], t2s[d], s);
    V3s[idx*128 + q] = s;
}

// e3 stats scan over V3xT: block = (q, half); all rows in block share channel q; 2 atomics/block
__global__ __launch_bounds__(256) void k_stats_v3scan(const f16* __restrict__ V3xT, float* __restrict__ acc3)
{
    const int q = blockIdx.x & 127, half = blockIdx.x >> 7;
    const int t = threadIdx.x, wave = t >> 6, lane = t & 63;
    float s = 0.f, s2 = 0.f;
    for (int j = half*256 + wave; j < half*256 + 256; j += 4) {
        size_t r = (size_t)q + 128*(size_t)j;
        f16x8 v = *reinterpret_cast<const f16x8*>(V3xT + r*512 + lane*8);
        #pragma unroll
        for (int e = 0; e < 8; ++e) { float f = (float)v[e]; s += f; s2 += f*f; }
    }
    #pragma unroll
    for (int off = 32; off; off >>= 1) { s += __shfl_xor(s, off); s2 += __shfl_xor(s2, off); }
    __shared__ float red[8];
    if (lane == 0) { red[wave] = s; red[4 + wave] = s2; }
    __syncthreads();
    if (t == 0) {
        atomicAdd(&acc3[q],       red[0]+red[1]+red[2]+red[3]);
        atomicAdd(&acc3[128 + q], red[4]+red[5]+red[6]+red[7]);
    }
}

__global__ void k_u(const float* __restrict__ V3s, const float* __restrict__ sc3, const float* __restrict__ sh3,
                    float* __restrict__ u1, float* __restrict__ u0)
{
    const int idx = blockIdx.x*256 + threadIdx.x;
    if (idx < 513*128) {
        int i = idx >> 7, q = idx & 127;
        float tv = lrelu(fmaf(sc3[q], V3s[idx], sh3[q]));
        if (i < 512) u1[idx] = tv; else u0[q] = tv;
    }
}

// ---------------- MFMA fw1 (stride 44) ----------------
__global__ __launch_bounds__(256) void k_mfma_fw1T(
    const f16* __restrict__ fW1h, const f16* __restrict__ V3xT,
    const float* __restrict__ sce3, const float* __restrict__ she3,
    const float* __restrict__ u1, const float* __restrict__ u0,
    const float* __restrict__ P1, const float* __restrict__ Ftot,
    f16* __restrict__ out6T)
{
    __shared__ __align__(16) f16 As[128][44];
    __shared__ __align__(16) f16 Bs[128][44];
    const int b = blockIdx.y;
    const int f0 = blockIdx.x * 128;
    const int t = threadIdx.x;
    const int wave = t >> 6, lane = t & 63;
    const int quad = lane >> 4, l16 = lane & 15;
    const int row0 = t >> 2, grp = t & 3;
    const f16* Aa = V3xT + (size_t)b*128*512;
    const float sc0 = sce3[row0], sh0 = she3[row0];
    const float sc1 = sce3[row0+64], sh1 = she3[row0+64];
    f32x4 acc[2][8];
    #pragma unroll
    for (int i = 0; i < 2; ++i)
        #pragma unroll
        for (int j = 0; j < 8; ++j) acc[i][j] = (f32x4){0.f,0.f,0.f,0.f};
    for (int k0 = 0; k0 < 512; k0 += 32) {
        #pragma unroll
        for (int p = 0; p < 2; ++p) {
            const int row = row0 + 64*p;
            const float sc = p ? sc1 : sc0, sh = p ? sh1 : sh0;
            f16x8 v = *reinterpret_cast<const f16x8*>(Aa + (size_t)row*512 + k0 + grp*8);
            f16x8 o;
            #pragma unroll
            for (int e = 0; e < 8; ++e) o[e] = (f16)lrelu(fmaf(sc, (float)v[e], sh));
            *reinterpret_cast<f16x8*>(&As[row][grp*8]) = o;
            f16x8 wv = *reinterpret_cast<const f16x8*>(fW1h + (size_t)(f0+row)*512 + k0 + grp*8);
            *reinterpret_cast<f16x8*>(&Bs[row][grp*8]) = wv;
        }
        __syncthreads();
        f16x8 a0 = *reinterpret_cast<const f16x8*>(&As[32*wave + l16][quad*8]);
        f16x8 a1 = *reinterpret_cast<const f16x8*>(&As[32*wave + 16 + l16][quad*8]);
        #pragma unroll
        for (int j = 0; j < 8; ++j) {
            f16x8 bj = *reinterpret_cast<const f16x8*>(&Bs[16*j + l16][quad*8]);
            acc[0][j] = __builtin_amdgcn_mfma_f32_16x16x32_f16(a0, bj, acc[0][j], 0, 0, 0);
            acc[1][j] = __builtin_amdgcn_mfma_f32_16x16x32_f16(a1, bj, acc[1][j], 0, 0, 0);
        }
        __syncthreads();
    }
    float p1j[8], p0j[8];
    #pragma unroll
    for (int j = 0; j < 8; ++j) {
        int f = f0 + 16*j + l16;
        p1j[j] = P1[b*1024 + f];
        p0j[j] = Ftot[f] - p1j[j];
    }
    #pragma unroll
    for (int i = 0; i < 2; ++i) {
        #pragma unroll
        for (int r = 0; r < 4; ++r) {
            int q = 32*wave + 16*i + quad*4 + r;
            float u1q = u1[b*128 + q], u0q = u0[q];
            #pragma unroll
            for (int j = 0; j < 8; ++j) {
                int f = f0 + 16*j + l16;
                out6T[((size_t)b*128 + q)*1024 + f] = (f16)(acc[i][j][r] + u1q*p1j[j] + u0q*p0j[j]);
            }
        }
    }
}

// ---------------- MFMA fw2 (stride 44) ----------------
__global__ __launch_bounds__(256) void k_mfma_fw2T(
    const f16* __restrict__ fW2h, const f16* __restrict__ out6T,
    const float* __restrict__ scf, const float* __restrict__ shf,
    const float* __restrict__ fbias2, f16* __restrict__ out7)
{
    __shared__ __align__(16) f16 As[128][44];
    __shared__ __align__(16) f16 Bs[128][44];
    const int b = blockIdx.y;
    const int o0 = blockIdx.x * 128;
    const int t = threadIdx.x;
    const int wave = t >> 6, lane = t & 63;
    const int quad = lane >> 4, l16 = lane & 15;
    const int row0 = t >> 2, grp = t & 3;
    const f16* Bb = out6T + (size_t)b*128*1024;
    f32x4 acc[2][8];
    #pragma unroll
    for (int i = 0; i < 2; ++i)
        #pragma unroll
        for (int j = 0; j < 8; ++j) acc[i][j] = (f32x4){0.f,0.f,0.f,0.f};
    for (int k0 = 0; k0 < 1024; k0 += 32) {
        float4 c0 = *reinterpret_cast<const float4*>(scf + k0 + grp*8);
        float4 c1 = *reinterpret_cast<const float4*>(scf + k0 + grp*8 + 4);
        float4 h0 = *reinterpret_cast<const float4*>(shf + k0 + grp*8);
        float4 h1 = *reinterpret_cast<const float4*>(shf + k0 + grp*8 + 4);
        float scv[8] = {c0.x,c0.y,c0.z,c0.w,c1.x,c1.y,c1.z,c1.w};
        float shv[8] = {h0.x,h0.y,h0.z,h0.w,h1.x,h1.y,h1.z,h1.w};
        #pragma unroll
        for (int p = 0; p < 2; ++p) {
            const int row = row0 + 64*p;
            f16x8 wv = *reinterpret_cast<const f16x8*>(fW2h + (size_t)(o0+row)*1024 + k0 + grp*8);
            *reinterpret_cast<f16x8*>(&As[row][grp*8]) = wv;
            f16x8 v = *reinterpret_cast<const f16x8*>(Bb + (size_t)row*1024 + k0 + grp*8);
            f16x8 o;
            #pragma unroll
            for (int e = 0; e < 8; ++e) o[e] = (f16)lrelu(fmaf(scv[e], (float)v[e], shv[e]));
            *reinterpret_cast<f16x8*>(&Bs[row][grp*8]) = o;
        }
        __syncthreads();
        f16x8 a0 = *reinterpret_cast<const f16x8*>(&As[32*wave + l16][quad*8]);
        f16x8 a1 = *reinterpret_cast<const f16x8*>(&As[32*wave + 16 + l16][quad*8]);
        #pragma unroll
        for (int j = 0; j < 8; ++j) {
            f16x8 bj = *reinterpret_cast<const f16x8*>(&Bs[16*j + l16][quad*8]);
            acc[0][j] = __builtin_amdgcn_mfma_f32_16x16x32_f16(a0, bj, acc[0][j], 0, 0, 0);
            acc[1][j] = __builtin_amdgcn_mfma_f32_16x16x32_f16(a1, bj, acc[1][j], 0, 0, 0);
        }
        __syncthreads();
    }
    #pragma unroll
    for (int i = 0; i < 2; ++i) {
        #pragma unroll
        for (int r = 0; r < 4; ++r) {
            int o = o0 + 32*wave + 16*i + quad*4 + r;
            float bias = fbias2[o];
            #pragma unroll
            for (int j = 0; j < 8; ++j) {
                int q = 16*j + l16;
                out7[((size_t)b*512 + o)*128 + q] = (f16)(acc[i][j][r] + bias);
            }
        }
    }
}

// ---------------- MFMA d1 (stride 44) ----------------
__global__ __launch_bounds__(256) void k_mfma_d1(
    const f16* __restrict__ dW1h, const f16* __restrict__ out7, float* __restrict__ d1pre)
{
    __shared__ __align__(16) f16 As[64][44];
    __shared__ __align__(16) f16 Bs[128][44];
    const int b = blockIdx.y, o0 = blockIdx.x * 128;
    const int t = threadIdx.x;
    const int wave = t >> 6, lane = t & 63;
    const int quad = lane >> 4, l16 = lane & 15;
    const int row0 = t >> 2, grp = t & 3;
    const f16* Bb = out7 + (size_t)b*65536;
    f32x4 acc[8];
    #pragma unroll
    for (int j = 0; j < 8; ++j) acc[j] = (f32x4){0.f,0.f,0.f,0.f};
    for (int k0 = 0; k0 < 128; k0 += 32) {
        *reinterpret_cast<f16x8*>(&As[row0][grp*8]) =
            *reinterpret_cast<const f16x8*>(dW1h + row0*128 + k0 + grp*8);
        #pragma unroll
        for (int p = 0; p < 2; ++p) {
            const int row = row0 + 64*p;
            *reinterpret_cast<f16x8*>(&Bs[row][grp*8]) =
                *reinterpret_cast<const f16x8*>(Bb + (size_t)(o0+row)*128 + k0 + grp*8);
        }
        __syncthreads();
        f16x8 a0 = *reinterpret_cast<const f16x8*>(&As[16*wave + l16][quad*8]);
        #pragma unroll
        for (int j = 0; j < 8; ++j) {
            f16x8 bj = *reinterpret_cast<const f16x8*>(&Bs[16*j + l16][quad*8]);
            acc[j] = __builtin_amdgcn_mfma_f32_16x16x32_f16(a0, bj, acc[j], 0, 0, 0);
        }
        __syncthreads();
    }
    #pragma unroll
    for (int r = 0; r < 4; ++r) {
        int d = 16*wave + quad*4 + r;
        #pragma unroll
        for (int j = 0; j < 8; ++j) {
            int o = o0 + 16*j + l16;
            d1pre[(size_t)b*32768 + (size_t)d*512 + o] = acc[j][r];
        }
    }
}

// row-major per-channel (sum,sumsq) partials for f16 [R][1024]; atomicAdd into acc[2048]
__global__ __launch_bounds__(256) void k_stats_rows_f16(
    const f16* __restrict__ buf, float* __restrict__ acc)
{
    const int t = threadIdx.x;
    const int c8 = (t & 127) * 8, rl = t >> 7;
    const size_t r0 = (size_t)blockIdx.x * 256;
    float s[8] = {0,0,0,0,0,0,0,0}, s2[8] = {0,0,0,0,0,0,0,0};
    for (int rr = rl; rr < 256; rr += 2) {
        f16x8 v = *reinterpret_cast<const f16x8*>(buf + (r0 + rr)*1024 + c8);
        #pragma unroll
        for (int e = 0; e < 8; ++e) { float f = (float)v[e]; s[e] += f; s2[e] += f*f; }
    }
    __shared__ float red[128*16];
    if (rl == 1) {
        #pragma unroll
        for (int e = 0; e < 8; ++e) { red[(t&127)*16 + e] = s[e]; red[(t&127)*16 + 8 + e] = s2[e]; }
    }
    __syncthreads();
    if (rl == 0) {
        #pragma unroll
        for (int e = 0; e < 8; ++e) {
            atomicAdd(&acc[c8 + e],        s[e]  + red[t*16 + e]);
            atomicAdd(&acc[1024 + c8 + e], s2[e] + red[t*16 + 8 + e]);
        }
    }
}

// split per-channel stats for f32 buf[b][C][512]
__global__ __launch_bounds__(256) void k_stats_cols_f32(
    const float* __restrict__ buf, int C, float* __restrict__ acc)
{
    const int b = blockIdx.x;
    const int c = blockIdx.y*8 + (threadIdx.x >> 5);
    const int ol = threadIdx.x & 31;
    const float* p = buf + ((size_t)b*C + c)*512;
    float s = 0.f, s2 = 0.f;
    #pragma unroll
    for (int i = 0; i < 16; ++i) { float v = p[ol + 32*i]; s += v; s2 += v*v; }
    #pragma unroll
    for (int off = 16; off; off >>= 1) { s += __shfl_xor(s, off); s2 += __shfl_xor(s2, off); }
    if (ol == 0) { atomicAdd(&acc[c], s); atomicAdd(&acc[C + c], s2); }
}

// d2: C[e,o] = sum_d dW2[e,d] * lrelu(sc*d1pre[b][d][o]+sh)
__global__ __launch_bounds__(128) void k_gemm_d2(
    const float* __restrict__ dW2, const float* __restrict__ d1pre,
    const float* __restrict__ scd, const float* __restrict__ shd, float* __restrict__ d2pre)
{
    __shared__ __align__(16) float As[16][36];
    __shared__ __align__(16) float Bs[16][68];
    const int n0 = blockIdx.x * 64, b = blockIdx.y;
    const int t = threadIdx.x;
    const int kk = t & 15, ri = t >> 4;
    const int qv = t & 63, kh = t >> 6;
    const int tx = t & 15, ty = t >> 4;
    float acc[4][4] = {{0.f,0.f,0.f,0.f},{0.f,0.f,0.f,0.f},{0.f,0.f,0.f,0.f},{0.f,0.f,0.f,0.f}};
    for (int k0 = 0; k0 < 64; k0 += 16) {
        #pragma unroll
        for (int mm = 0; mm < 4; ++mm)
            As[kk][ri + mm*8] = dW2[(ri + mm*8)*64 + k0 + kk];
        #pragma unroll
        for (int ki = 0; ki < 8; ++ki) {
            int d = k0 + kh + ki*2;
            float v = d1pre[(size_t)b*32768 + (size_t)d*512 + n0 + qv];
            Bs[kh + ki*2][qv] = lrelu(fmaf(scd[d], v, shd[d]));
        }
        __syncthreads();
        #pragma unroll
        for (int kq = 0; kq < 16; ++kq) {
            const float4 av = *reinterpret_cast<const float4*>(&As[kq][ty*4]);
            const float4 bv = *reinterpret_cast<const float4*>(&Bs[kq][tx*4]);
            FMA44(av, bv);
        }
        __syncthreads();
    }
    #pragma unroll
    for (int i = 0; i < 4; ++i)
        #pragma unroll
        for (int j = 0; j < 4; ++j)
            d2pre[(size_t)b*16384 + (size_t)(ty*4 + i)*512 + n0 + tx*4 + j] = acc[i][j];
}

__global__ __launch_bounds__(256) void k_d3(
    const float* __restrict__ d2pre, const float* __restrict__ dW3,
    const float* __restrict__ sce, const float* __restrict__ she,
    const float* __restrict__ dbias3, float* __restrict__ out)
{
    const int idx = blockIdx.x*256 + threadIdx.x;
    const int b = idx >> 9, o = idx & 511;
    float s = dbias3[0];
    for (int e = 0; e < 32; ++e) {
        float v = d2pre[(size_t)b*16384 + e*512 + o];
        s = fmaf(dW3[e], lrelu(fmaf(v, sce[e], she[e])), s);
    }
    out[idx] = s;
}

extern "C" void kernel_launch(void* const* d_in, const int* in_sizes, int n_in,
                              void* d_out, int out_size, void* d_ws, size_t ws_size,
                              hipStream_t stream)
{
    (void)in_sizes; (void)n_in; (void)out_size;
    const float* x      = (const float*)d_in[0];
    const float* gumbel = (const float*)d_in[1];
    const float* cW1 = (const float*)d_in[2];
    const float* cg1 = (const float*)d_in[3];
    const float* cb1 = (const float*)d_in[4];
    const float* cW2 = (const float*)d_in[5];
    const float* cg2 = (const float*)d_in[6];
    const float* cb2 = (const float*)d_in[7];
    const float* cW3 = (const float*)d_in[8];
    const float* cg3 = (const float*)d_in[9];
    const float* cb3 = (const float*)d_in[10];
    const float* eW1 = (const float*)d_in[11];
    const float* eg1 = (const float*)d_in[12];
    const float* eb1 = (const float*)d_in[13];
    const float* eW2 = (const float*)d_in[14];
    const float* eg2 = (const float*)d_in[15];
    const float* eb2 = (const float*)d_in[16];
    const float* eW3 = (const float*)d_in[17];
    const float* eg3 = (const float*)d_in[18];
    const float* eb3 = (const float*)d_in[19];
    const float* fW1 = (const float*)d_in[20];
    const float* fg1 = (const float*)d_in[21];
    const float* fb1 = (const float*)d_in[22];
    const float* fW2 = (const float*)d_in[23];
    const float* fbias2 = (const float*)d_in[24];
    const float* dW1 = (const float*)d_in[25];
    const float* dg1 = (const float*)d_in[26];
    const float* db1 = (const float*)d_in[27];
    const float* dW2 = (const float*)d_in[28];
    const float* dg2 = (const float*)d_in[29];
    const float* db2 = (const float*)d_in[30];
    const float* dW3 = (const float*)d_in[31];
    const float* dbias3 = (const float*)d_in[32];
    float* out = (float*)d_out;
    float* ws  = (float*)d_ws;

    if (ws_size < O_END * sizeof(float)) {
        k_sentinel<<<1024,256,0,stream>>>(out);
        return;
    }

    float* H1  = ws + O_H1;
    float* H2  = ws + O_H2;
    float* L   = ws + O_L;
    int*   sel = (int*)(ws + O_SEL);
    float* S   = ws + O_S;
    float* S2  = ws + O_S2;
    float* val = ws + O_VAL;
    float* prm = ws + O_PRM;
    f16*   fW1h= (f16*)(ws + O_FW1H);
    f16*   fW2h= (f16*)(ws + O_FW2H);
    float* accF= ws + O_ACCF;
    float* accD1= ws + O_ACCD1;
    float* accD2= ws + O_ACCD2;
    f16*   dW1h= (f16*)(ws + O_DW1H);
    f16*   eW3h= (f16*)(ws + O_EW3H);
    float* V2s = ws + O_V2SS;
    float* u1  = ws + O_U1;
    float* P1  = ws + O_P1;
    float* fzT = ws + O_FZT;
    float* V3s = ws + O_V3S;
    f16*   V3xT= (f16*)(ws + O_BIG1);
    f16*   out7= (f16*)(ws + O_BIG1);   // aliases V3xT (dead after fw1)
    f16*   out6T=(f16*)(ws + O_BIG2);
    f16*   V2x = (f16*)(ws + O_BIG2);   // aliases out6T (V2x dead before fw1 writes out6T)
    float* d1p = ws + O_D1;             // aliases out6T (dead after fw2)
    float* d2p = ws + O_D2;

    const float invN_e = 1.0f/1310720.f;

    // ---- c-path (deterministic fp32; feeds argmax) ----
    k_gemm_c<<<dim3(16,8),256,0,stream>>>(x,  cW1, H1, 1024, 512,  nullptr,     nullptr);
    k_stats2d<<<1024,256,0,stream>>>(H1, 1024, cg1, cb1, prm+P_SC1, prm+P_SH1);
    k_gemm_c<<<dim3(16,8),256,0,stream>>>(H1, cW2, H2, 1024, 1024, prm+P_SC1, prm+P_SH1);
    k_stats2d<<<1024,256,0,stream>>>(H2, 1024, cg2, cb2, prm+P_SC2, prm+P_SH2);
    k_gemm_c<<<dim3(32,8),256,0,stream>>>(H2, cW3, L,  2048, 1024, prm+P_SC2, prm+P_SH2);
    k_stats2d<<<2048,256,0,stream>>>(L, 2048, cg3, cb3, prm+P_SC3, prm+P_SH3);
    k_sel<<<512,256,0,stream>>>(L, gumbel, prm+P_SC3, prm+P_SH3, sel);

    // ---- weight prep (overwrites L region) + selection-derived helpers ----
    k_prep<<<2048,256,0,stream>>>(fW1, fW2, dW1, eW3, fW1h, fW2h, dW1h, eW3h, accF);
    k_val<<<512,256,0,stream>>>(x, S, S2, val);
    k_e1params<<<1,256,0,stream>>>(S, S2, val, eW1, eg1, eb1, prm+P_A1, prm+P_C1, prm+P_ACC2);
    k_transpose_fz<<<dim3(32,16),256,0,stream>>>(fW1, fzT);
    k_wtrans2<<<1,256,0,stream>>>(eW2, prm+P_EW2T);
    k_ftot<<<4,256,0,stream>>>(fzT, prm+P_FTOT);
    k_p1<<<512,256,0,stream>>>(fzT, sel, P1);

    // ---- e-path ----
    k_epass2<<<1024,256,0,stream>>>(x, prm+P_A1, prm+P_C1, prm+P_EW2T, V2x);
    k_esupport2<<<513,64,0,stream>>>(val, prm+P_A1, prm+P_C1, prm+P_EW2T, V2s);
    k_stats_v2scan<<<64,256,0,stream>>>(V2x, prm+P_ACC2);
    k_wstats<<<64,64,0,stream>>>(V2s, 64, prm+P_ACC2);
    k_finalize<<<1,256,0,stream>>>(prm+P_ACC2, 64, invN_e, eg2, eb2, prm+P_SCE2, prm+P_SHE2);
    k_mfma_e3<<<dim3(4,512),256,0,stream>>>(eW3h, V2x, prm+P_SCE2, prm+P_SHE2, V3xT);
    k_esupport3<<<513,128,0,stream>>>(V2s, prm+P_SCE2, prm+P_SHE2, eW3, V3s);
    k_stats_v3scan<<<256,256,0,stream>>>(V3xT, prm+P_ACC3);
    k_wstats<<<128,64,0,stream>>>(V3s, 128, prm+P_ACC3);
    k_finalize<<<1,256,0,stream>>>(prm+P_ACC3, 128, invN_e, eg3, eb3, prm+P_SCE3, prm+P_SHE3);
    k_u<<<257,256,0,stream>>>(V3s, prm+P_SCE3, prm+P_SHE3, u1, prm+P_U0);

    // ---- f-path (MFMA f16) ----
    k_mfma_fw1T<<<dim3(8,512),256,0,stream>>>(fW1h, V3xT, prm+P_SCE3, prm+P_SHE3,
                                              u1, prm+P_U0, P1, prm+P_FTOT, out6T);
    k_stats_rows_f16<<<256,256,0,stream>>>(out6T, accF);
    k_finalize<<<4,256,0,stream>>>(accF, 1024, 1.0f/65536.f, fg1, fb1, prm+P_SCF1, prm+P_SHF1);
    k_mfma_fw2T<<<dim3(4,512),256,0,stream>>>(fW2h, out6T, prm+P_SCF1, prm+P_SHF1, fbias2, out7);

    // ---- d-path ----
    k_mfma_d1<<<dim3(4,512),256,0,stream>>>(dW1h, out7, d1p);
    k_stats_cols_f32<<<dim3(512,8),256,0,stream>>>(d1p, 64, accD1);
    k_finalize<<<1,256,0,stream>>>(accD1, 64, 1.0f/262144.f, dg1, db1, prm+P_SCD1, prm+P_SHD1);
    k_gemm_d2<<<dim3(8,512),128,0,stream>>>(dW2, d1p, prm+P_SCD1, prm+P_SHD1, d2p);
    k_stats_cols_f32<<<dim3(512,4),256,0,stream>>>(d2p, 32, accD2);
    k_finalize<<<1,256,0,stream>>>(accD2, 32, 1.0f/262144.f, dg2, db2, prm+P_SCD2, prm+P_SHD2);
    k_d3<<<1024,256,0,stream>>>(d2p, dW3, prm+P_SCD2, prm+P_SHD2, dbias3, out);
}